// Round 4
// baseline (472.078 us; speedup 1.0000x reference)
//
#include <hip/hip_runtime.h>

#define HID 512
#define OUTD 7
#define EPSV 1e-5f
#define PR 32     // pool_reduce output rows

typedef __attribute__((ext_vector_type(8))) short bf16x8;
typedef __attribute__((ext_vector_type(4))) float f32x4;
typedef __attribute__((ext_vector_type(2))) float f32x2;
typedef unsigned short ushort_t;
typedef unsigned int uint_t;
typedef unsigned char uchar_t;

// ---------------- bf16 helpers ----------------
__device__ __forceinline__ ushort_t f2bf(float f) {
    uint_t u = __float_as_uint(f);
    u = (u + 0x7fffu + ((u >> 16) & 1u)) >> 16;    // RNE
    return (ushort_t)u;
}
__device__ __forceinline__ float bflo(uint_t u) { return __uint_as_float(u << 16); }
__device__ __forceinline__ float bfhi(uint_t u) { return __uint_as_float(u & 0xffff0000u); }

// ---------------- fp8 e4m3 (OCP) helpers — HW cvt ----------------
__device__ __forceinline__ void dec4(uint_t v, float* f) {
    f32x2 p0 = __builtin_amdgcn_cvt_pk_f32_fp8(v, false);
    f32x2 p1 = __builtin_amdgcn_cvt_pk_f32_fp8(v, true);
    f[0] = p0.x; f[1] = p0.y; f[2] = p1.x; f[3] = p1.y;
}
__device__ __forceinline__ uint_t enc4(float a, float b, float c, float d) {
    uint_t r = __builtin_amdgcn_cvt_pk_fp8_f32(a, b, 0, false);
    r = __builtin_amdgcn_cvt_pk_fp8_f32(c, d, r, true);
    return r;
}

// async global->LDS, 16B per lane; LDS dest is wave-uniform base + lane*16
__device__ __forceinline__ void gload_lds16(const ushort_t* g, ushort_t* l) {
    __builtin_amdgcn_global_load_lds(
        (const __attribute__((address_space(1))) uint_t*)g,
        (__attribute__((address_space(3))) uint_t*)l, 16, 0, 0);
}

// ---------------- setup: deg count + weight transpose (merged, independent) ------
// Wt emitted in MFMA-FRAGMENT layout Wf[n16][kc][l16][8 bf16] (n16=n>>4,
// l16=n&15, kc=k>>3): GEMM B-fragment load = one coalesced 1KB load per wave.
__global__ __launch_bounds__(256) void deg_wtrans(
        const int* __restrict__ dst, int* __restrict__ deg, int E, int degB,
        const float* __restrict__ W0, const float* __restrict__ W1,
        const float* __restrict__ W2, const float* __restrict__ W3,
        ushort_t* __restrict__ T0, ushort_t* __restrict__ T1,
        ushort_t* __restrict__ T2, ushort_t* __restrict__ T3) {
    __shared__ ushort_t tile[32][33];
    if ((int)blockIdx.x < degB) {
        int e = blockIdx.x * 256 + threadIdx.x;
        if (e < E) atomicAdd(&deg[dst[e]], 1);
        return;
    }
    int id = blockIdx.x - degB;
    const float* W; ushort_t* T; int K;
    if (id < 64)       { W = W0; T = T0; K = 128; }
    else if (id < 320) { W = W1; T = T1; K = 512; id -= 64; }
    else if (id < 576) { W = W2; T = T2; K = 512; id -= 320; }
    else               { W = W3; T = T3; K = 512; id -= 576; }
    const int tn = id & 15;        // n-tile (512/32)
    const int tk = id >> 4;        // k-tile
    const int t = threadIdx.x;
    const int r = t >> 3;          // 0..31
    const int c4 = (t & 7) * 4;    // 0,4,..,28
    const float4 v = *(const float4*)&W[(size_t)(tk * 32 + r) * HID + tn * 32 + c4];
    tile[r][c4 + 0] = f2bf(v.x); tile[r][c4 + 1] = f2bf(v.y);
    tile[r][c4 + 2] = f2bf(v.z); tile[r][c4 + 3] = f2bf(v.w);
    __syncthreads();
    ushort4 ov = make_ushort4(tile[c4 + 0][r], tile[c4 + 1][r],
                              tile[c4 + 2][r], tile[c4 + 3][r]);
    // fragment-layout address
    const int n   = tn * 32 + r;          // output row (col of W)
    const int n16 = n >> 4, l16n = n & 15;
    const int kb  = tk * 32 + c4;         // k of first element
    const int kc  = kb >> 3, k8 = kb & 7; // k8 in {0,4}
    size_t idx = ((((size_t)n16 * (K >> 3) + kc) << 4) + l16n) * 8 + k8;
    *(ushort4*)&T[idx] = ov;
}

// ---------------- hierarchical scan (2 phases) ----------------

__global__ void scan1(const int* __restrict__ deg, int* __restrict__ off,
                      int* __restrict__ partial, float* __restrict__ dinv, int N) {
    __shared__ int s[256];
    const int t = threadIdx.x;
    const int i = blockIdx.x * 256 + t;
    int d = (i < N) ? deg[i] : 0;
    if (i < N) dinv[i] = rsqrtf((float)(d + 1));   // +1 self loop
    s[t] = d;
    __syncthreads();
#pragma unroll
    for (int ofs = 1; ofs < 256; ofs <<= 1) {
        int v = (t >= ofs) ? s[t - ofs] : 0;
        __syncthreads();
        s[t] += v;
        __syncthreads();
    }
    if (i < N) off[i] = s[t] - d;
    if (t == 255) partial[blockIdx.x] = s[255];
}

__global__ void scan23(int* __restrict__ off, const int* __restrict__ partial,
                       int* __restrict__ cursor, int N, int E, int nb) {
    __shared__ int s[256];
    __shared__ int ex[256];
    const int t = threadIdx.x;
    int d = (t < nb) ? partial[t] : 0;
    s[t] = d;
    __syncthreads();
#pragma unroll
    for (int ofs = 1; ofs < 256; ofs <<= 1) {
        int v = (t >= ofs) ? s[t - ofs] : 0;
        __syncthreads();
        s[t] += v;
        __syncthreads();
    }
    ex[t] = s[t] - d;
    __syncthreads();
    int i = blockIdx.x * 256 + t;
    if (i < N) {
        int v = off[i] + ex[i >> 8];
        off[i] = v;
        cursor[i] = v;
    } else if (i == N) {
        off[N] = E;
    }
}

// ---------------- fused: CSR fill + x -> fp8*dinv ----------------

__global__ void fill_cvt(const int* __restrict__ src, const int* __restrict__ dst,
                         int* __restrict__ cursor, int* __restrict__ srcs, int E,
                         const float* __restrict__ x, const float* __restrict__ dinv,
                         ushort_t* __restrict__ xb, int pairs) {
    int i = blockIdx.x * blockDim.x + threadIdx.x;
    if (i < E) { int p = atomicAdd(&cursor[dst[i]], 1); srcs[p] = src[i]; return; }
    i -= E;
    if (i < pairs) {
        float dr = dinv[i >> 6];                      // row = 2i/128
        float a = x[2 * i] * dr, b = x[2 * i + 1] * dr;
        uint_t d = __builtin_amdgcn_cvt_pk_fp8_f32(a, b, 0, false);
        xb[i] = (ushort_t)(d & 0xffffu);
    }
}

// ---------------- aggregation (512-dim layers): COLUMN-CHUNKED fp8 gather ----------------
// R19: the 10MB gather source exceeds the 4MB per-XCD L2 (40% hit, rest from
// ~5TB/s L3 -> ~35us/layer). Split cols into 4 chunks of 128 (blockIdx.y =
// chunk, slow dispatch index): working set/chunk = 2.5MB -> L2-RESIDENT on
// every XCD; 164MB/layer of edge traffic now at L2 speed. Same bytes, same
// load-instr count (8 edge-rows x 128B = 1KB/instr). 2-deep gather ILP.

__global__ __launch_bounds__(256) void csr_agg_col(
        const uchar_t* __restrict__ xs, const int* __restrict__ off,
        const int* __restrict__ srcs, const float* __restrict__ dinv,
        ushort_t* __restrict__ ax, int N) {
    const int r = blockIdx.x * 4 + (threadIdx.x >> 6);
    if (r >= N) return;
    const int c = blockIdx.y;              // 128-col chunk, 4 total
    const int lane = threadIdx.x & 63;
    const int eg = lane >> 3;              // 8 edge slots
    const int sc = lane & 7;               // 8 x 16B subchunks = 128 B
    const uint4* xb = (const uint4*)xs;    // fp8 row = 32 uint4 (512 B)
    const int cbase = c * 8 + sc;
    float a[16];
    if (eg == 0) {                         // self loop
        uint4 v = xb[(size_t)r * 32 + cbase];
        dec4(v.x, a); dec4(v.y, a + 4); dec4(v.z, a + 8); dec4(v.w, a + 12);
    } else {
#pragma unroll
        for (int q = 0; q < 16; q++) a[q] = 0.f;
    }
    int e = off[r];
    const int e1 = off[r + 1];
    for (; e + 16 <= e1; e += 16) {        // 2 gathers in flight
        int s0 = srcs[e + eg], s1 = srcs[e + 8 + eg];
        uint4 v0 = xb[(size_t)s0 * 32 + cbase];
        uint4 v1 = xb[(size_t)s1 * 32 + cbase];
        float f[16];
        dec4(v0.x, f); dec4(v0.y, f + 4); dec4(v0.z, f + 8); dec4(v0.w, f + 12);
#pragma unroll
        for (int q = 0; q < 16; q++) a[q] += f[q];
        dec4(v1.x, f); dec4(v1.y, f + 4); dec4(v1.z, f + 8); dec4(v1.w, f + 12);
#pragma unroll
        for (int q = 0; q < 16; q++) a[q] += f[q];
    }
    for (; e < e1; e += 8) {
        int idx = e + eg;
        bool valid = idx < e1;
        int s = srcs[valid ? idx : e];
        uint4 v = xb[(size_t)s * 32 + cbase];
        if (!valid) { v.x = 0; v.y = 0; v.z = 0; v.w = 0; }
        float f[16];
        dec4(v.x, f); dec4(v.y, f + 4); dec4(v.z, f + 8); dec4(v.w, f + 12);
#pragma unroll
        for (int q = 0; q < 16; q++) a[q] += f[q];
    }
#pragma unroll
    for (int q = 0; q < 16; q++) a[q] += __shfl_xor(a[q], 8);
#pragma unroll
    for (int q = 0; q < 16; q++) a[q] += __shfl_xor(a[q], 16);
#pragma unroll
    for (int q = 0; q < 16; q++) a[q] += __shfl_xor(a[q], 32);
    if (lane < 16) {                       // all lanes hold full sums post-butterfly
        const float dr = dinv[r];
        const int b = (lane >> 3) * 8;     // half of this sc's 16 values
        const int osc = lane & 7;
        uint_t w0 = (uint_t)f2bf(a[b + 0] * dr) | ((uint_t)f2bf(a[b + 1] * dr) << 16);
        uint_t w1 = (uint_t)f2bf(a[b + 2] * dr) | ((uint_t)f2bf(a[b + 3] * dr) << 16);
        uint_t w2 = (uint_t)f2bf(a[b + 4] * dr) | ((uint_t)f2bf(a[b + 5] * dr) << 16);
        uint_t w3 = (uint_t)f2bf(a[b + 6] * dr) | ((uint_t)f2bf(a[b + 7] * dr) << 16);
        ((uint4*)ax)[(size_t)r * 64 + c * 16 + osc * 2 + (lane >> 3)] =
            make_uint4(w0, w1, w2, w3);
    }
}

// layer-0 aggregation (128-dim input, 2.5MB source — already L2-scale)
__global__ __launch_bounds__(256) void csr_agg_128(
        const uchar_t* __restrict__ xs, const int* __restrict__ off,
        const int* __restrict__ srcs, const float* __restrict__ dinv,
        ushort_t* __restrict__ ax, int N) {
    int gtid = blockIdx.x * 256 + threadIdx.x;
    int r = gtid >> 6, lane = gtid & 63;
    if (r >= N) return;
    const int sub = lane >> 3, l8 = lane & 7;   // 8 edge slots x 8 col-chunks (16B)
    const uint4* xb = (const uint4*)xs;         // row stride = 8 uint4 (128 B)
    float a[16];
    if (sub == 0) {
        uint4 v = xb[(size_t)r * 8 + l8];
        dec4(v.x, a); dec4(v.y, a + 4); dec4(v.z, a + 8); dec4(v.w, a + 12);
    } else {
#pragma unroll
        for (int q = 0; q < 16; q++) a[q] = 0.f;
    }
    const int e1 = off[r + 1];
    for (int e = off[r]; e < e1; e += 8) {
        int idx = e + sub;
        bool valid = idx < e1;
        int s = srcs[valid ? idx : e];
        uint4 v = xb[(size_t)s * 8 + l8];
        if (!valid) { v.x = 0; v.y = 0; v.z = 0; v.w = 0; }
        float f[16];
        dec4(v.x, f); dec4(v.y, f + 4); dec4(v.z, f + 8); dec4(v.w, f + 12);
#pragma unroll
        for (int q = 0; q < 16; q++) a[q] += f[q];
    }
#pragma unroll
    for (int q = 0; q < 16; q++) a[q] += __shfl_xor(a[q], 8);
#pragma unroll
    for (int q = 0; q < 16; q++) a[q] += __shfl_xor(a[q], 16);
#pragma unroll
    for (int q = 0; q < 16; q++) a[q] += __shfl_xor(a[q], 32);
    if (sub < 2) {
        float dr = dinv[r];
        const int b = sub * 8;
        uint_t w0 = (uint_t)f2bf(a[b + 0] * dr) | ((uint_t)f2bf(a[b + 1] * dr) << 16);
        uint_t w1 = (uint_t)f2bf(a[b + 2] * dr) | ((uint_t)f2bf(a[b + 3] * dr) << 16);
        uint_t w2 = (uint_t)f2bf(a[b + 4] * dr) | ((uint_t)f2bf(a[b + 5] * dr) << 16);
        uint_t w3 = (uint_t)f2bf(a[b + 6] * dr) | ((uint_t)f2bf(a[b + 7] * dr) << 16);
        ((uint4*)ax)[(size_t)r * 16 + l8 * 2 + sub] = make_uint4(w0, w1, w2, w3);
    }
}

// ---------------- fused MFMA GEMM + LayerNorm(+ReLU) epilogue ----------------
// R19: 32 rows x FULL 512 cols, 4 waves (256 thr) -> 625 blocks = 2.4/CU
// (R18's 313x512thr = 1.2 blocks/CU, 2 waves/SIMD -> L2-latency exposed at
// every barrier). BK=128 (4 K-stages for K=512, half the vmcnt(0) drains);
// K templated so the 4-kk inner body fully unrolls and B-fragment loads
// burst-issue. B read straight from L2-resident Wf (fragment layout, 1KB
// coalesced per load). A staged via gload_lds with ck^=(row&7) XOR swizzle
// (16 chunks/row): ds_read conflict-free (2-way max = free).
// Wave owns 32 rows x 128 cols: acc[2 im][8 jn], OPERAND-SWAPPED
// mfma(bfr, af) -> lane owns row im*16+l16, cols wn+jn*16+quad*4+rg.

template<int POOL, int K>
__global__ __launch_bounds__(256) void gemm_ln(
        const ushort_t* __restrict__ A, const ushort_t* __restrict__ Wf,
        const float* __restrict__ bias, const float* __restrict__ gamma,
        const float* __restrict__ beta, const float* __restrict__ dinv,
        uchar_t* __restrict__ out8, float* __restrict__ pbuf, int M) {
    __shared__ __align__(16) ushort_t AsL[32 * 128];   // 8 KB (32 rows x 256B)
    __shared__ float sred[4][32][2];
    const int t = threadIdx.x;
    const int wave = t >> 6, lane = t & 63;
    const int m0 = blockIdx.x * 32;
    const int wn = wave * 128;
    const int quad = lane >> 4, l16 = lane & 15;
    const int K8 = K >> 3;

    f32x4 acc[2][8];
#pragma unroll
    for (int im = 0; im < 2; im++)
#pragma unroll
        for (int jn = 0; jn < 8; jn++) acc[im][jn] = (f32x4){0.f, 0.f, 0.f, 0.f};

    // staging map: this wave stages rows [wave*8, wave*8+8), 2 rounds of 4 rows
    const int srow4 = lane >> 4;               // row within 4-row group
    const int ckd   = lane & 15;               // dest 16B chunk 0..15
#pragma unroll 1
    for (int k0 = 0; k0 < K; k0 += 128) {
#pragma unroll
        for (int j = 0; j < 2; j++) {
            const int rr = wave * 8 + j * 4 + srow4;   // tile row 0..31
            int gm = m0 + rr;
            if (gm >= M) gm = M - 1;
            const int cks = ckd ^ (rr & 7);            // inverse-swizzled source chunk
            gload_lds16(A + (size_t)gm * K + k0 + cks * 8,
                        AsL + (size_t)wave * 1024 + j * 512);
        }
        __syncthreads();
#pragma unroll
        for (int kk = 0; kk < 4; kk++) {
            const int kc = (k0 >> 3) + kk * 4 + quad;  // global 16B k-chunk
            bf16x8 bfr[8], af[2];
#pragma unroll
            for (int jn = 0; jn < 8; jn++)
                bfr[jn] = *(const bf16x8*)
                    &Wf[((((size_t)(wave * 8 + jn) * K8 + kc) << 4) + l16) * 8];
            const int ckr = (kk * 4 + quad) ^ (l16 & 7);
#pragma unroll
            for (int im = 0; im < 2; im++)
                af[im] = *(const bf16x8*)((const char*)AsL
                              + (im * 16 + l16) * 256 + ckr * 16);
#pragma unroll
            for (int im = 0; im < 2; im++)
#pragma unroll
                for (int jn = 0; jn < 8; jn++)
                    acc[im][jn] = __builtin_amdgcn_mfma_f32_16x16x32_bf16(
                                      bfr[jn], af[im], acc[im][jn], 0, 0, 0);   // SWAPPED
        }
        __syncthreads();
    }

    // ---- epilogue: lane owns rows m0+im*16+l16, cols wn+jn*16+quad*4+rg ----
    float4 bias4[8];
#pragma unroll
    for (int jn = 0; jn < 8; jn++)
        bias4[jn] = *(const float4*)&bias[wn + jn * 16 + quad * 4];

#pragma unroll
    for (int im = 0; im < 2; im++) {
        float s = 0.f, q = 0.f;
#pragma unroll
        for (int jn = 0; jn < 8; jn++) {
#pragma unroll
            for (int rg = 0; rg < 4; rg++) {
                float h = acc[im][jn][rg] + ((const float*)&bias4[jn])[rg];
                s += h; q += h * h;
            }
        }
        s += __shfl_xor(s, 16); s += __shfl_xor(s, 32);
        q += __shfl_xor(q, 16); q += __shfl_xor(q, 32);
        if (quad == 0) { sred[wave][im * 16 + l16][0] = s; sred[wave][im * 16 + l16][1] = q; }
    }
    __syncthreads();

    float cacc[8][4];
    if (POOL) {
#pragma unroll
        for (int jn = 0; jn < 8; jn++)
#pragma unroll
            for (int rg = 0; rg < 4; rg++) cacc[jn][rg] = 0.f;
    }

#pragma unroll
    for (int im = 0; im < 2; im++) {
        const int row = im * 16 + l16;
        const float st = sred[0][row][0] + sred[1][row][0] + sred[2][row][0] + sred[3][row][0];
        const float qt = sred[0][row][1] + sred[1][row][1] + sred[2][row][1] + sred[3][row][1];
        const float mu = st * (1.0f / HID);
        const float var = qt * (1.0f / HID) - mu * mu;
        const float rs = rsqrtf(var + EPSV);
        const int gm = m0 + row;
        const bool ok = gm < M;
        float dr = 0.f;
        if (!POOL) dr = ok ? dinv[gm] : 0.f;
#pragma unroll
        for (int jn = 0; jn < 8; jn++) {
            const float4 g4 = *(const float4*)&gamma[wn + jn * 16 + quad * 4];
            const float4 b4 = *(const float4*)&beta[wn + jn * 16 + quad * 4];
            float o[4];
#pragma unroll
            for (int rg = 0; rg < 4; rg++) {
                float h = acc[im][jn][rg] + ((const float*)&bias4[jn])[rg];
                o[rg] = fmaxf((h - mu) * rs * ((const float*)&g4)[rg]
                              + ((const float*)&b4)[rg], 0.f);
            }
            if (POOL) {
#pragma unroll
                for (int rg = 0; rg < 4; rg++) cacc[jn][rg] += ok ? o[rg] : 0.f;
            } else if (ok) {
                *(uint_t*)(out8 + (size_t)gm * HID + wn + jn * 16 + quad * 4) =
                    enc4(o[0] * dr, o[1] * dr, o[2] * dr, o[3] * dr);
            }
        }
    }

    if (POOL) {
        // reduce column sums over the 16 l16-lanes (rows), then one writer/quad
#pragma unroll
        for (int jn = 0; jn < 8; jn++)
#pragma unroll
            for (int rg = 0; rg < 4; rg++) {
                float v = cacc[jn][rg];
                v += __shfl_xor(v, 1); v += __shfl_xor(v, 2);
                v += __shfl_xor(v, 4); v += __shfl_xor(v, 8);
                cacc[jn][rg] = v;
            }
        if (l16 == 0) {
#pragma unroll
            for (int jn = 0; jn < 8; jn++) {
                float4 v = make_float4(cacc[jn][0], cacc[jn][1], cacc[jn][2], cacc[jn][3]);
                *(float4*)&pbuf[(size_t)blockIdx.x * HID + wn + jn * 16 + quad * 4] = v;
            }
        }
    }
}

// ---------------- hierarchical pool partial reduction: NB rows -> PR rows ----------------

__global__ __launch_bounds__(256) void pool_reduce(
        const float* __restrict__ pbuf, float* __restrict__ pbuf2, int NB) {
    const int t = threadIdx.x;
    const int b = blockIdx.x;
    const int R = (NB + PR - 1) / PR;
    float2 s = make_float2(0.f, 0.f);
    for (int u = 0; u < R; u++) {
        int r = b * R + u;
        if (r < NB) {
            const float2 v = ((const float2*)(pbuf + (size_t)r * HID))[t];
            s.x += v.x; s.y += v.y;
        }
    }
    ((float2*)(pbuf2 + (size_t)b * HID))[t] = s;
}

// ---------------- output head: reduce PR partials + project to 7 outs ----------------

__global__ void out_kernel(const float* __restrict__ pbuf2, const float* __restrict__ Wout,
                           const float* __restrict__ bout, float* __restrict__ out, int N) {
    __shared__ float red[256];
    int t = threadIdx.x;
    float g0 = 0.f, g1 = 0.f;
#pragma unroll
    for (int p = 0; p < PR; p += 8) {
#pragma unroll
        for (int u = 0; u < 8; u++) {
            const float2 v = ((const float2*)(pbuf2 + (size_t)(p + u) * HID))[t];
            g0 += v.x; g1 += v.y;
        }
    }
    float invn = 1.0f / (float)N;
    for (int o = 0; o < OUTD; o++) {
        float pr = g0 * Wout[(2 * t) * OUTD + o] + g1 * Wout[(2 * t + 1) * OUTD + o];
        red[t] = pr;
        __syncthreads();
        for (int sft = 128; sft > 0; sft >>= 1) {
            if (t < sft) red[t] += red[t + sft];
            __syncthreads();
        }
        if (t == 0) out[o] = red[0] * invn + bout[o];
        __syncthreads();
    }
}

// ---------------- launch ----------------

extern "C" void kernel_launch(void* const* d_in, const int* in_sizes, int n_in,
                              void* d_out, int out_size, void* d_ws, size_t ws_size,
                              hipStream_t stream) {
    const float* x  = (const float*)d_in[0];
    const int*   ei = (const int*)d_in[1];
    const int N = in_sizes[0] / 128;
    const int E = in_sizes[1] / 2;
    const int* src = ei;
    const int* dst = ei + E;
    const float* Ws[4] = {(const float*)d_in[2], (const float*)d_in[4],
                          (const float*)d_in[6], (const float*)d_in[8]};
    const float* bs[4] = {(const float*)d_in[3], (const float*)d_in[5],
                          (const float*)d_in[7], (const float*)d_in[9]};
    const float* gamma = (const float*)d_in[10];
    const float* beta  = (const float*)d_in[11];
    const float* Wout  = (const float*)d_in[12];
    const float* bout  = (const float*)d_in[13];
    float* out = (float*)d_out;

    const int NBM = (N + 31) / 32;                   // gemm_ln blocks (pool partial rows)

    // workspace layout (16B-aligned chunks first)
    char* p = (char*)d_ws;
    ushort_t* axb = (ushort_t*)p;  p += sizeof(ushort_t) * (size_t)N * HID;   // agg out bf16 (gemm A)
    uchar_t*  ho8 = (uchar_t*)p;   p += (size_t)N * HID;                      // fp8 LN out (agg input)
    uchar_t*  xb8 = ho8;           // alias: fp8 x (N*128B, pre-scaled) until gemm_ln(l0) overwrites
    ushort_t* Wt[4];
    Wt[0] = (ushort_t*)p;          p += sizeof(ushort_t) * 128 * HID;
    Wt[1] = (ushort_t*)p;          p += sizeof(ushort_t) * HID * HID;
    Wt[2] = (ushort_t*)p;          p += sizeof(ushort_t) * HID * HID;
    Wt[3] = (ushort_t*)p;          p += sizeof(ushort_t) * HID * HID;
    float* dinv  = (float*)p;      p += sizeof(float) * N;
    float* pbuf  = (float*)p;      p += sizeof(float) * (size_t)(NBM + 4) * HID; // pool partials
    float* pbuf2 = (float*)p;      p += sizeof(float) * PR * HID;             // 64 KB stage-2
    int* deg    = (int*)p;         p += sizeof(int) * N;
    int* off    = (int*)p;         p += sizeof(int) * (N + 4);
    int* cursor = (int*)p;         p += sizeof(int) * N;
    int* partial= (int*)p;         p += sizeof(int) * 256;
    int* srcs   = (int*)p;         // E ints

    const int nb = (N + 255) / 256;
    const int degB = (E + 255) / 256;

    // ---- setup: CSR build + conversions (once) ----
    hipMemsetAsync(deg, 0, sizeof(int) * N, stream);   // memset node: graph-capturable
    deg_wtrans<<<degB + 832, 256, 0, stream>>>(dst, deg, E, degB,
                                               Ws[0], Ws[1], Ws[2], Ws[3],
                                               Wt[0], Wt[1], Wt[2], Wt[3]);
    scan1<<<nb, 256, 0, stream>>>(deg, off, partial, dinv, N);
    scan23<<<(N + 256) / 256, 256, 0, stream>>>(off, partial, cursor, N, E, nb);
    {
        int pairs = N * 64;   // N*128/2
        int tot = E + pairs;
        fill_cvt<<<(tot + 255) / 256, 256, 0, stream>>>(src, dst, cursor, srcs, E,
                                                        x, dinv, (ushort_t*)xb8, pairs);
    }

    const dim3 aggGrid((N + 3) / 4, 4);
    for (int l = 0; l < 4; l++) {
        if (l == 0)
            csr_agg_128<<<(N * 64 + 255) / 256, 256, 0, stream>>>(xb8, off, srcs, dinv, axb, N);
        else
            csr_agg_col<<<aggGrid, 256, 0, stream>>>(ho8, off, srcs, dinv, axb, N);
        if (l == 0)
            gemm_ln<0, 128><<<NBM, 256, 0, stream>>>(axb, Wt[0], bs[0], gamma, beta, dinv,
                                                     ho8, pbuf, N);
        else if (l < 3)
            gemm_ln<0, 512><<<NBM, 256, 0, stream>>>(axb, Wt[l], bs[l], gamma, beta, dinv,
                                                     ho8, pbuf, N);
        else
            gemm_ln<1, 512><<<NBM, 256, 0, stream>>>(axb, Wt[l], bs[l], gamma, beta, dinv,
                                                     ho8, pbuf, N);
    }
    pool_reduce<<<PR, 256, 0, stream>>>(pbuf, pbuf2, NBM);
    out_kernel<<<1, 256, 0, stream>>>(pbuf2, Wout, bout, out, N);
}

// Round 5
// 392.979 us; speedup vs baseline: 1.2013x; 1.2013x over previous
//
#include <hip/hip_runtime.h>

#define HID 512
#define OUTD 7
#define EPSV 1e-5f
#define PR 32     // pool_reduce output rows

typedef __attribute__((ext_vector_type(8))) short bf16x8;
typedef __attribute__((ext_vector_type(4))) float f32x4;
typedef __attribute__((ext_vector_type(2))) float f32x2;
typedef unsigned short ushort_t;
typedef unsigned int uint_t;
typedef unsigned char uchar_t;

// ---------------- bf16 helpers ----------------
__device__ __forceinline__ ushort_t f2bf(float f) {
    uint_t u = __float_as_uint(f);
    u = (u + 0x7fffu + ((u >> 16) & 1u)) >> 16;    // RNE
    return (ushort_t)u;
}
__device__ __forceinline__ float bflo(uint_t u) { return __uint_as_float(u << 16); }
__device__ __forceinline__ float bfhi(uint_t u) { return __uint_as_float(u & 0xffff0000u); }

// ---------------- fp8 e4m3 (OCP) helpers — HW cvt ----------------
// R20: accumulate as f32x2 straight off the cvt_pk pairs -> v_pk_add_f32
// (16 instrs per 16 values vs 24 with scalar adds; agg was 85% VALUBusy).
__device__ __forceinline__ void acc16(const uint4& v, f32x2* a) {
    a[0] += __builtin_amdgcn_cvt_pk_f32_fp8(v.x, false);
    a[1] += __builtin_amdgcn_cvt_pk_f32_fp8(v.x, true);
    a[2] += __builtin_amdgcn_cvt_pk_f32_fp8(v.y, false);
    a[3] += __builtin_amdgcn_cvt_pk_f32_fp8(v.y, true);
    a[4] += __builtin_amdgcn_cvt_pk_f32_fp8(v.z, false);
    a[5] += __builtin_amdgcn_cvt_pk_f32_fp8(v.z, true);
    a[6] += __builtin_amdgcn_cvt_pk_f32_fp8(v.w, false);
    a[7] += __builtin_amdgcn_cvt_pk_f32_fp8(v.w, true);
}
__device__ __forceinline__ uint_t enc4(float a, float b, float c, float d) {
    uint_t r = __builtin_amdgcn_cvt_pk_fp8_f32(a, b, 0, false);
    r = __builtin_amdgcn_cvt_pk_fp8_f32(c, d, r, true);
    return r;
}

// async global->LDS, 16B per lane; LDS dest is wave-uniform base + lane*16
__device__ __forceinline__ void gload_lds16(const ushort_t* g, ushort_t* l) {
    __builtin_amdgcn_global_load_lds(
        (const __attribute__((address_space(1))) uint_t*)g,
        (__attribute__((address_space(3))) uint_t*)l, 16, 0, 0);
}

// ---------------- setup: deg count + weight transpose (merged, independent) ------
// Wt emitted in MFMA-FRAGMENT layout Wf[n16][kc][l16][8 bf16] (n16=n>>4,
// l16=n&15, kc=k>>3): GEMM B-fragment load = one coalesced 1KB load per wave.
__global__ __launch_bounds__(256) void deg_wtrans(
        const int* __restrict__ dst, int* __restrict__ deg, int E, int degB,
        const float* __restrict__ W0, const float* __restrict__ W1,
        const float* __restrict__ W2, const float* __restrict__ W3,
        ushort_t* __restrict__ T0, ushort_t* __restrict__ T1,
        ushort_t* __restrict__ T2, ushort_t* __restrict__ T3) {
    __shared__ ushort_t tile[32][33];
    if ((int)blockIdx.x < degB) {
        int e = blockIdx.x * 256 + threadIdx.x;
        if (e < E) atomicAdd(&deg[dst[e]], 1);
        return;
    }
    int id = blockIdx.x - degB;
    const float* W; ushort_t* T; int K;
    if (id < 64)       { W = W0; T = T0; K = 128; }
    else if (id < 320) { W = W1; T = T1; K = 512; id -= 64; }
    else if (id < 576) { W = W2; T = T2; K = 512; id -= 320; }
    else               { W = W3; T = T3; K = 512; id -= 576; }
    const int tn = id & 15;        // n-tile (512/32)
    const int tk = id >> 4;        // k-tile
    const int t = threadIdx.x;
    const int r = t >> 3;          // 0..31
    const int c4 = (t & 7) * 4;    // 0,4,..,28
    const float4 v = *(const float4*)&W[(size_t)(tk * 32 + r) * HID + tn * 32 + c4];
    tile[r][c4 + 0] = f2bf(v.x); tile[r][c4 + 1] = f2bf(v.y);
    tile[r][c4 + 2] = f2bf(v.z); tile[r][c4 + 3] = f2bf(v.w);
    __syncthreads();
    ushort4 ov = make_ushort4(tile[c4 + 0][r], tile[c4 + 1][r],
                              tile[c4 + 2][r], tile[c4 + 3][r]);
    // fragment-layout address
    const int n   = tn * 32 + r;          // output row (col of W)
    const int n16 = n >> 4, l16n = n & 15;
    const int kb  = tk * 32 + c4;         // k of first element
    const int kc  = kb >> 3, k8 = kb & 7; // k8 in {0,4}
    size_t idx = ((((size_t)n16 * (K >> 3) + kc) << 4) + l16n) * 8 + k8;
    *(ushort4*)&T[idx] = ov;
}

// ---------------- hierarchical scan (2 phases) ----------------

__global__ void scan1(const int* __restrict__ deg, int* __restrict__ off,
                      int* __restrict__ partial, float* __restrict__ dinv, int N) {
    __shared__ int s[256];
    const int t = threadIdx.x;
    const int i = blockIdx.x * 256 + t;
    int d = (i < N) ? deg[i] : 0;
    if (i < N) dinv[i] = rsqrtf((float)(d + 1));   // +1 self loop
    s[t] = d;
    __syncthreads();
#pragma unroll
    for (int ofs = 1; ofs < 256; ofs <<= 1) {
        int v = (t >= ofs) ? s[t - ofs] : 0;
        __syncthreads();
        s[t] += v;
        __syncthreads();
    }
    if (i < N) off[i] = s[t] - d;
    if (t == 255) partial[blockIdx.x] = s[255];
}

__global__ void scan23(int* __restrict__ off, const int* __restrict__ partial,
                       int* __restrict__ cursor, int N, int E, int nb) {
    __shared__ int s[256];
    __shared__ int ex[256];
    const int t = threadIdx.x;
    int d = (t < nb) ? partial[t] : 0;
    s[t] = d;
    __syncthreads();
#pragma unroll
    for (int ofs = 1; ofs < 256; ofs <<= 1) {
        int v = (t >= ofs) ? s[t - ofs] : 0;
        __syncthreads();
        s[t] += v;
        __syncthreads();
    }
    ex[t] = s[t] - d;
    __syncthreads();
    int i = blockIdx.x * 256 + t;
    if (i < N) {
        int v = off[i] + ex[i >> 8];
        off[i] = v;
        cursor[i] = v;
    } else if (i == N) {
        off[N] = E;
    }
}

// ---------------- fused: CSR fill + x -> fp8*dinv ----------------

__global__ void fill_cvt(const int* __restrict__ src, const int* __restrict__ dst,
                         int* __restrict__ cursor, int* __restrict__ srcs, int E,
                         const float* __restrict__ x, const float* __restrict__ dinv,
                         ushort_t* __restrict__ xb, int pairs) {
    int i = blockIdx.x * blockDim.x + threadIdx.x;
    if (i < E) { int p = atomicAdd(&cursor[dst[i]], 1); srcs[p] = src[i]; return; }
    i -= E;
    if (i < pairs) {
        float dr = dinv[i >> 6];                      // row = 2i/128
        float a = x[2 * i] * dr, b = x[2 * i + 1] * dr;
        uint_t d = __builtin_amdgcn_cvt_pk_fp8_f32(a, b, 0, false);
        xb[i] = (ushort_t)(d & 0xffffu);
    }
}

// ---------------- aggregation: fp8 gather, multi-edge wave-instructions ----------------
// R20: REVERTED to the R16 single-pass structure. R19's column-chunked variant
// (L2-locality play) was 65us/layer at 85% VALUBusy / 11% HBM — the gather is
// VALU-rate-bound, not L3-BW-bound, and chunking x4'd per-row fixed costs
// (butterfly 192 vs 16 shfl/row, 4x srcs re-reads). Locality fixes don't help
// a VALU-bound kernel. 4 gathers in flight (deeper ILP regressed, R15);
// f32x2 pk-accumulate cuts decode VALU ~33%.

__global__ __launch_bounds__(256) void csr_agg_512(
        const uchar_t* __restrict__ xs, const int* __restrict__ off,
        const int* __restrict__ srcs, const float* __restrict__ dinv,
        ushort_t* __restrict__ ax, int N) {
    int gtid = blockIdx.x * 256 + threadIdx.x;
    int r = gtid >> 6, lane = gtid & 63;
    if (r >= N) return;
    const int half = lane >> 5, l32 = lane & 31;
    const uint4* xb = (const uint4*)xs;    // row stride = 32 uint4 (512 B)
    f32x2 a[8];
#pragma unroll
    for (int q = 0; q < 8; q++) a[q] = (f32x2){0.f, 0.f};
    if (half == 0) {
        uint4 v = xb[(size_t)r * 32 + l32];
        acc16(v, a);
    }
    int e = off[r];
    const int e1 = off[r + 1];
    for (; e + 8 <= e1; e += 8) {
        int si[4]; uint4 vi[4];
#pragma unroll
        for (int j = 0; j < 4; j++) si[j] = srcs[e + 2 * j + half];
#pragma unroll
        for (int j = 0; j < 4; j++) vi[j] = xb[(size_t)si[j] * 32 + l32];
#pragma unroll
        for (int j = 0; j < 4; j++) acc16(vi[j], a);
    }
    for (; e < e1; e += 2) {
        int idx = e + half;
        bool valid = idx < e1;
        int s = srcs[valid ? idx : e];
        uint4 v = xb[(size_t)s * 32 + l32];
        if (!valid) { v.x = 0; v.y = 0; v.z = 0; v.w = 0; }
        acc16(v, a);
    }
#pragma unroll
    for (int q = 0; q < 8; q++) {
        a[q][0] += __shfl_xor(a[q][0], 32);
        a[q][1] += __shfl_xor(a[q][1], 32);
    }
    {
        // both halves hold full sums; half0 stores cols l32*16+0..7,
        // half1 stores cols l32*16+8..15  -> contiguous 1KB per wave
        float dr = dinv[r];
        const int b = half * 4;            // f32x2 index base
        uint_t w0 = (uint_t)f2bf(a[b + 0][0] * dr) | ((uint_t)f2bf(a[b + 0][1] * dr) << 16);
        uint_t w1 = (uint_t)f2bf(a[b + 1][0] * dr) | ((uint_t)f2bf(a[b + 1][1] * dr) << 16);
        uint_t w2 = (uint_t)f2bf(a[b + 2][0] * dr) | ((uint_t)f2bf(a[b + 2][1] * dr) << 16);
        uint_t w3 = (uint_t)f2bf(a[b + 3][0] * dr) | ((uint_t)f2bf(a[b + 3][1] * dr) << 16);
        ((uint4*)ax)[(size_t)r * 64 + l32 * 2 + half] = make_uint4(w0, w1, w2, w3);
    }
}

__global__ __launch_bounds__(256) void csr_agg_128(
        const uchar_t* __restrict__ xs, const int* __restrict__ off,
        const int* __restrict__ srcs, const float* __restrict__ dinv,
        ushort_t* __restrict__ ax, int N) {
    int gtid = blockIdx.x * 256 + threadIdx.x;
    int r = gtid >> 6, lane = gtid & 63;
    if (r >= N) return;
    const int sub = lane >> 3, l8 = lane & 7;   // 8 edge slots x 8 col-chunks (16B)
    const uint4* xb = (const uint4*)xs;         // row stride = 8 uint4 (128 B)
    f32x2 a[8];
#pragma unroll
    for (int q = 0; q < 8; q++) a[q] = (f32x2){0.f, 0.f};
    if (sub == 0) {
        uint4 v = xb[(size_t)r * 8 + l8];
        acc16(v, a);
    }
    const int e1 = off[r + 1];
    for (int e = off[r]; e < e1; e += 8) {
        int idx = e + sub;
        bool valid = idx < e1;
        int s = srcs[valid ? idx : e];
        uint4 v = xb[(size_t)s * 8 + l8];
        if (!valid) { v.x = 0; v.y = 0; v.z = 0; v.w = 0; }
        acc16(v, a);
    }
#pragma unroll
    for (int q = 0; q < 8; q++) {
        a[q][0] += __shfl_xor(a[q][0], 8);  a[q][1] += __shfl_xor(a[q][1], 8);
        a[q][0] += __shfl_xor(a[q][0], 16); a[q][1] += __shfl_xor(a[q][1], 16);
        a[q][0] += __shfl_xor(a[q][0], 32); a[q][1] += __shfl_xor(a[q][1], 32);
    }
    if (sub < 2) {
        float dr = dinv[r];
        const int b = sub * 4;
        uint_t w0 = (uint_t)f2bf(a[b + 0][0] * dr) | ((uint_t)f2bf(a[b + 0][1] * dr) << 16);
        uint_t w1 = (uint_t)f2bf(a[b + 1][0] * dr) | ((uint_t)f2bf(a[b + 1][1] * dr) << 16);
        uint_t w2 = (uint_t)f2bf(a[b + 2][0] * dr) | ((uint_t)f2bf(a[b + 2][1] * dr) << 16);
        uint_t w3 = (uint_t)f2bf(a[b + 3][0] * dr) | ((uint_t)f2bf(a[b + 3][1] * dr) << 16);
        ((uint4*)ax)[(size_t)r * 16 + l8 * 2 + sub] = make_uint4(w0, w1, w2, w3);
    }
}

// ---------------- fused MFMA GEMM + LayerNorm(+ReLU) epilogue ----------------
// R19 geometry (kept): 32 rows x FULL 512 cols, 4 waves, 625 blocks = 2.4/CU.
// BK=128 (4 K-stages for K=512); K templated so inner body fully unrolls.
// B read straight from L2-resident Wf (fragment layout, 1KB coalesced/load).
// A staged via gload_lds with ck^=(row&7) XOR swizzle; ds_read conflict-free.
// Wave owns 32 rows x 128 cols: acc[2 im][8 jn], OPERAND-SWAPPED
// mfma(bfr, af) -> lane owns row im*16+l16, cols wn+jn*16+quad*4+rg.

template<int POOL, int K>
__global__ __launch_bounds__(256) void gemm_ln(
        const ushort_t* __restrict__ A, const ushort_t* __restrict__ Wf,
        const float* __restrict__ bias, const float* __restrict__ gamma,
        const float* __restrict__ beta, const float* __restrict__ dinv,
        uchar_t* __restrict__ out8, float* __restrict__ pbuf, int M) {
    __shared__ __align__(16) ushort_t AsL[32 * 128];   // 8 KB (32 rows x 256B)
    __shared__ float sred[4][32][2];
    const int t = threadIdx.x;
    const int wave = t >> 6, lane = t & 63;
    const int m0 = blockIdx.x * 32;
    const int wn = wave * 128;
    const int quad = lane >> 4, l16 = lane & 15;
    const int K8 = K >> 3;

    f32x4 acc[2][8];
#pragma unroll
    for (int im = 0; im < 2; im++)
#pragma unroll
        for (int jn = 0; jn < 8; jn++) acc[im][jn] = (f32x4){0.f, 0.f, 0.f, 0.f};

    // staging map: this wave stages rows [wave*8, wave*8+8), 2 rounds of 4 rows
    const int srow4 = lane >> 4;               // row within 4-row group
    const int ckd   = lane & 15;               // dest 16B chunk 0..15
#pragma unroll 1
    for (int k0 = 0; k0 < K; k0 += 128) {
#pragma unroll
        for (int j = 0; j < 2; j++) {
            const int rr = wave * 8 + j * 4 + srow4;   // tile row 0..31
            int gm = m0 + rr;
            if (gm >= M) gm = M - 1;
            const int cks = ckd ^ (rr & 7);            // inverse-swizzled source chunk
            gload_lds16(A + (size_t)gm * K + k0 + cks * 8,
                        AsL + (size_t)wave * 1024 + j * 512);
        }
        __syncthreads();
#pragma unroll
        for (int kk = 0; kk < 4; kk++) {
            const int kc = (k0 >> 3) + kk * 4 + quad;  // global 16B k-chunk
            bf16x8 bfr[8], af[2];
#pragma unroll
            for (int jn = 0; jn < 8; jn++)
                bfr[jn] = *(const bf16x8*)
                    &Wf[((((size_t)(wave * 8 + jn) * K8 + kc) << 4) + l16) * 8];
            const int ckr = (kk * 4 + quad) ^ (l16 & 7);
#pragma unroll
            for (int im = 0; im < 2; im++)
                af[im] = *(const bf16x8*)((const char*)AsL
                              + (im * 16 + l16) * 256 + ckr * 16);
#pragma unroll
            for (int im = 0; im < 2; im++)
#pragma unroll
                for (int jn = 0; jn < 8; jn++)
                    acc[im][jn] = __builtin_amdgcn_mfma_f32_16x16x32_bf16(
                                      bfr[jn], af[im], acc[im][jn], 0, 0, 0);   // SWAPPED
        }
        __syncthreads();
    }

    // ---- epilogue: lane owns rows m0+im*16+l16, cols wn+jn*16+quad*4+rg ----
    float4 bias4[8];
#pragma unroll
    for (int jn = 0; jn < 8; jn++)
        bias4[jn] = *(const float4*)&bias[wn + jn * 16 + quad * 4];

#pragma unroll
    for (int im = 0; im < 2; im++) {
        float s = 0.f, q = 0.f;
#pragma unroll
        for (int jn = 0; jn < 8; jn++) {
#pragma unroll
            for (int rg = 0; rg < 4; rg++) {
                float h = acc[im][jn][rg] + ((const float*)&bias4[jn])[rg];
                s += h; q += h * h;
            }
        }
        s += __shfl_xor(s, 16); s += __shfl_xor(s, 32);
        q += __shfl_xor(q, 16); q += __shfl_xor(q, 32);
        if (quad == 0) { sred[wave][im * 16 + l16][0] = s; sred[wave][im * 16 + l16][1] = q; }
    }
    __syncthreads();

    float cacc[8][4];
    if (POOL) {
#pragma unroll
        for (int jn = 0; jn < 8; jn++)
#pragma unroll
            for (int rg = 0; rg < 4; rg++) cacc[jn][rg] = 0.f;
    }

#pragma unroll
    for (int im = 0; im < 2; im++) {
        const int row = im * 16 + l16;
        const float st = sred[0][row][0] + sred[1][row][0] + sred[2][row][0] + sred[3][row][0];
        const float qt = sred[0][row][1] + sred[1][row][1] + sred[2][row][1] + sred[3][row][1];
        const float mu = st * (1.0f / HID);
        const float var = qt * (1.0f / HID) - mu * mu;
        const float rs = rsqrtf(var + EPSV);
        const int gm = m0 + row;
        const bool ok = gm < M;
        float dr = 0.f;
        if (!POOL) dr = ok ? dinv[gm] : 0.f;
#pragma unroll
        for (int jn = 0; jn < 8; jn++) {
            const float4 g4 = *(const float4*)&gamma[wn + jn * 16 + quad * 4];
            const float4 b4 = *(const float4*)&beta[wn + jn * 16 + quad * 4];
            float o[4];
#pragma unroll
            for (int rg = 0; rg < 4; rg++) {
                float h = acc[im][jn][rg] + ((const float*)&bias4[jn])[rg];
                o[rg] = fmaxf((h - mu) * rs * ((const float*)&g4)[rg]
                              + ((const float*)&b4)[rg], 0.f);
            }
            if (POOL) {
#pragma unroll
                for (int rg = 0; rg < 4; rg++) cacc[jn][rg] += ok ? o[rg] : 0.f;
            } else if (ok) {
                *(uint_t*)(out8 + (size_t)gm * HID + wn + jn * 16 + quad * 4) =
                    enc4(o[0] * dr, o[1] * dr, o[2] * dr, o[3] * dr);
            }
        }
    }

    if (POOL) {
        // reduce column sums over the 16 l16-lanes (rows), then one writer/quad
#pragma unroll
        for (int jn = 0; jn < 8; jn++)
#pragma unroll
            for (int rg = 0; rg < 4; rg++) {
                float v = cacc[jn][rg];
                v += __shfl_xor(v, 1); v += __shfl_xor(v, 2);
                v += __shfl_xor(v, 4); v += __shfl_xor(v, 8);
                cacc[jn][rg] = v;
            }
        if (l16 == 0) {
#pragma unroll
            for (int jn = 0; jn < 8; jn++) {
                float4 v = make_float4(cacc[jn][0], cacc[jn][1], cacc[jn][2], cacc[jn][3]);
                *(float4*)&pbuf[(size_t)blockIdx.x * HID + wn + jn * 16 + quad * 4] = v;
            }
        }
    }
}

// ---------------- hierarchical pool partial reduction: NB rows -> PR rows ----------------

__global__ __launch_bounds__(256) void pool_reduce(
        const float* __restrict__ pbuf, float* __restrict__ pbuf2, int NB) {
    const int t = threadIdx.x;
    const int b = blockIdx.x;
    const int R = (NB + PR - 1) / PR;
    float2 s = make_float2(0.f, 0.f);
    for (int u = 0; u < R; u++) {
        int r = b * R + u;
        if (r < NB) {
            const float2 v = ((const float2*)(pbuf + (size_t)r * HID))[t];
            s.x += v.x; s.y += v.y;
        }
    }
    ((float2*)(pbuf2 + (size_t)b * HID))[t] = s;
}

// ---------------- output head: reduce PR partials + project to 7 outs ----------------

__global__ void out_kernel(const float* __restrict__ pbuf2, const float* __restrict__ Wout,
                           const float* __restrict__ bout, float* __restrict__ out, int N) {
    __shared__ float red[256];
    int t = threadIdx.x;
    float g0 = 0.f, g1 = 0.f;
#pragma unroll
    for (int p = 0; p < PR; p += 8) {
#pragma unroll
        for (int u = 0; u < 8; u++) {
            const float2 v = ((const float2*)(pbuf2 + (size_t)(p + u) * HID))[t];
            g0 += v.x; g1 += v.y;
        }
    }
    float invn = 1.0f / (float)N;
    for (int o = 0; o < OUTD; o++) {
        float pr = g0 * Wout[(2 * t) * OUTD + o] + g1 * Wout[(2 * t + 1) * OUTD + o];
        red[t] = pr;
        __syncthreads();
        for (int sft = 128; sft > 0; sft >>= 1) {
            if (t < sft) red[t] += red[t + sft];
            __syncthreads();
        }
        if (t == 0) out[o] = red[0] * invn + bout[o];
        __syncthreads();
    }
}

// ---------------- launch ----------------

extern "C" void kernel_launch(void* const* d_in, const int* in_sizes, int n_in,
                              void* d_out, int out_size, void* d_ws, size_t ws_size,
                              hipStream_t stream) {
    const float* x  = (const float*)d_in[0];
    const int*   ei = (const int*)d_in[1];
    const int N = in_sizes[0] / 128;
    const int E = in_sizes[1] / 2;
    const int* src = ei;
    const int* dst = ei + E;
    const float* Ws[4] = {(const float*)d_in[2], (const float*)d_in[4],
                          (const float*)d_in[6], (const float*)d_in[8]};
    const float* bs[4] = {(const float*)d_in[3], (const float*)d_in[5],
                          (const float*)d_in[7], (const float*)d_in[9]};
    const float* gamma = (const float*)d_in[10];
    const float* beta  = (const float*)d_in[11];
    const float* Wout  = (const float*)d_in[12];
    const float* bout  = (const float*)d_in[13];
    float* out = (float*)d_out;

    const int NBM = (N + 31) / 32;                   // gemm_ln blocks (pool partial rows)

    // workspace layout (16B-aligned chunks first)
    char* p = (char*)d_ws;
    ushort_t* axb = (ushort_t*)p;  p += sizeof(ushort_t) * (size_t)N * HID;   // agg out bf16 (gemm A)
    uchar_t*  ho8 = (uchar_t*)p;   p += (size_t)N * HID;                      // fp8 LN out (agg input)
    uchar_t*  xb8 = ho8;           // alias: fp8 x (N*128B, pre-scaled) until gemm_ln(l0) overwrites
    ushort_t* Wt[4];
    Wt[0] = (ushort_t*)p;          p += sizeof(ushort_t) * 128 * HID;
    Wt[1] = (ushort_t*)p;          p += sizeof(ushort_t) * HID * HID;
    Wt[2] = (ushort_t*)p;          p += sizeof(ushort_t) * HID * HID;
    Wt[3] = (ushort_t*)p;          p += sizeof(ushort_t) * HID * HID;
    float* dinv  = (float*)p;      p += sizeof(float) * N;
    float* pbuf  = (float*)p;      p += sizeof(float) * (size_t)(NBM + 4) * HID; // pool partials
    float* pbuf2 = (float*)p;      p += sizeof(float) * PR * HID;             // 64 KB stage-2
    int* deg    = (int*)p;         p += sizeof(int) * N;
    int* off    = (int*)p;         p += sizeof(int) * (N + 4);
    int* cursor = (int*)p;         p += sizeof(int) * N;
    int* partial= (int*)p;         p += sizeof(int) * 256;
    int* srcs   = (int*)p;         // E ints

    const int nb = (N + 255) / 256;
    const int degB = (E + 255) / 256;

    // ---- setup: CSR build + conversions (once) ----
    hipMemsetAsync(deg, 0, sizeof(int) * N, stream);   // memset node: graph-capturable
    deg_wtrans<<<degB + 832, 256, 0, stream>>>(dst, deg, E, degB,
                                               Ws[0], Ws[1], Ws[2], Ws[3],
                                               Wt[0], Wt[1], Wt[2], Wt[3]);
    scan1<<<nb, 256, 0, stream>>>(deg, off, partial, dinv, N);
    scan23<<<(N + 256) / 256, 256, 0, stream>>>(off, partial, cursor, N, E, nb);
    {
        int pairs = N * 64;   // N*128/2
        int tot = E + pairs;
        fill_cvt<<<(tot + 255) / 256, 256, 0, stream>>>(src, dst, cursor, srcs, E,
                                                        x, dinv, (ushort_t*)xb8, pairs);
    }

    for (int l = 0; l < 4; l++) {
        if (l == 0)
            csr_agg_128<<<(N * 64 + 255) / 256, 256, 0, stream>>>(xb8, off, srcs, dinv, axb, N);
        else
            csr_agg_512<<<(N * 64 + 255) / 256, 256, 0, stream>>>(ho8, off, srcs, dinv, axb, N);
        if (l == 0)
            gemm_ln<0, 128><<<NBM, 256, 0, stream>>>(axb, Wt[0], bs[0], gamma, beta, dinv,
                                                     ho8, pbuf, N);
        else if (l < 3)
            gemm_ln<0, 512><<<NBM, 256, 0, stream>>>(axb, Wt[l], bs[l], gamma, beta, dinv,
                                                     ho8, pbuf, N);
        else
            gemm_ln<1, 512><<<NBM, 256, 0, stream>>>(axb, Wt[l], bs[l], gamma, beta, dinv,
                                                     ho8, pbuf, N);
    }
    pool_reduce<<<PR, 256, 0, stream>>>(pbuf, pbuf2, NBM);
    out_kernel<<<1, 256, 0, stream>>>(pbuf2, Wout, bout, out, N);
}

// Round 6
// 362.457 us; speedup vs baseline: 1.3024x; 1.0842x over previous
//
#include <hip/hip_runtime.h>

#define HID 512
#define OUTD 7
#define EPSV 1e-5f
#define PB 256    // ln_pool blocks (partial buffer rows)
#define PR 32     // pool_reduce output rows

typedef __attribute__((ext_vector_type(8))) short bf16x8;
typedef __attribute__((ext_vector_type(4))) float f32x4;
typedef __attribute__((ext_vector_type(2))) float f32x2;
typedef unsigned short ushort_t;
typedef unsigned int uint_t;
typedef unsigned char uchar_t;

// ---------------- bf16 helpers ----------------
__device__ __forceinline__ ushort_t f2bf(float f) {
    uint_t u = __float_as_uint(f);
    u = (u + 0x7fffu + ((u >> 16) & 1u)) >> 16;    // RNE
    return (ushort_t)u;
}
__device__ __forceinline__ float bflo(uint_t u) { return __uint_as_float(u << 16); }
__device__ __forceinline__ float bfhi(uint_t u) { return __uint_as_float(u & 0xffff0000u); }

// ---------------- fp8 e4m3 (OCP) helpers — HW cvt ----------------
// R21: accumulate as f32x2 straight off the cvt_pk pairs -> v_pk_add_f32
// (16 instrs per 16 values vs 24 with scalar adds; agg is the VALU-heaviest
// kernel in the pipeline). Validated numerically in R20.
__device__ __forceinline__ void acc16(const uint4& v, f32x2* a) {
    a[0] += __builtin_amdgcn_cvt_pk_f32_fp8(v.x, false);
    a[1] += __builtin_amdgcn_cvt_pk_f32_fp8(v.x, true);
    a[2] += __builtin_amdgcn_cvt_pk_f32_fp8(v.y, false);
    a[3] += __builtin_amdgcn_cvt_pk_f32_fp8(v.y, true);
    a[4] += __builtin_amdgcn_cvt_pk_f32_fp8(v.z, false);
    a[5] += __builtin_amdgcn_cvt_pk_f32_fp8(v.z, true);
    a[6] += __builtin_amdgcn_cvt_pk_f32_fp8(v.w, false);
    a[7] += __builtin_amdgcn_cvt_pk_f32_fp8(v.w, true);
}
__device__ __forceinline__ uint_t enc4(float a, float b, float c, float d) {
    uint_t r = __builtin_amdgcn_cvt_pk_fp8_f32(a, b, 0, false);
    r = __builtin_amdgcn_cvt_pk_fp8_f32(c, d, r, true);
    return r;
}

// async global->LDS, 16B per lane; LDS dest is wave-uniform base + lane*16
__device__ __forceinline__ void gload_lds16(const ushort_t* g, ushort_t* l) {
    __builtin_amdgcn_global_load_lds(
        (const __attribute__((address_space(1))) uint_t*)g,
        (__attribute__((address_space(3))) uint_t*)l, 16, 0, 0);
}

// ---------------- setup: deg count + weight transpose (merged, independent) ----------------
// R21 NOTE: reverted to ROW-MAJOR Wt[512][K] (the R16-proven GEMM stages B via
// global_load_lds). The fragment-layout + B-from-global fused variants
// (R17-R20) all lost to this structure: B loads inside the MFMA dependency
// chain can't be hoisted at VGPR budget -> repeated exposed L2 latency.
__global__ __launch_bounds__(256) void deg_wtrans(
        const int* __restrict__ dst, int* __restrict__ deg, int E, int degB,
        const float* __restrict__ W0, const float* __restrict__ W1,
        const float* __restrict__ W2, const float* __restrict__ W3,
        ushort_t* __restrict__ T0, ushort_t* __restrict__ T1,
        ushort_t* __restrict__ T2, ushort_t* __restrict__ T3) {
    __shared__ ushort_t tile[32][33];
    if ((int)blockIdx.x < degB) {
        int e = blockIdx.x * 256 + threadIdx.x;
        if (e < E) atomicAdd(&deg[dst[e]], 1);
        return;
    }
    int id = blockIdx.x - degB;
    const float* W; ushort_t* T; int K;
    if (id < 64)       { W = W0; T = T0; K = 128; }
    else if (id < 320) { W = W1; T = T1; K = 512; id -= 64; }
    else if (id < 576) { W = W2; T = T2; K = 512; id -= 320; }
    else               { W = W3; T = T3; K = 512; id -= 576; }
    const int tn = id & 15;        // n-tile (512/32)
    const int tk = id >> 4;        // k-tile
    const int t = threadIdx.x;
    const int r = t >> 3;          // 0..31
    const int c4 = (t & 7) * 4;    // 0,4,..,28
    const float4 v = *(const float4*)&W[(size_t)(tk * 32 + r) * HID + tn * 32 + c4];
    tile[r][c4 + 0] = f2bf(v.x); tile[r][c4 + 1] = f2bf(v.y);
    tile[r][c4 + 2] = f2bf(v.z); tile[r][c4 + 3] = f2bf(v.w);
    __syncthreads();
    ushort4 ov = make_ushort4(tile[c4 + 0][r], tile[c4 + 1][r],
                              tile[c4 + 2][r], tile[c4 + 3][r]);
    *(ushort4*)&T[(size_t)(tn * 32 + r) * K + tk * 32 + c4] = ov;
}

// ---------------- hierarchical scan (2 phases) ----------------

__global__ void scan1(const int* __restrict__ deg, int* __restrict__ off,
                      int* __restrict__ partial, float* __restrict__ dinv, int N) {
    __shared__ int s[256];
    const int t = threadIdx.x;
    const int i = blockIdx.x * 256 + t;
    int d = (i < N) ? deg[i] : 0;
    if (i < N) dinv[i] = rsqrtf((float)(d + 1));   // +1 self loop
    s[t] = d;
    __syncthreads();
#pragma unroll
    for (int ofs = 1; ofs < 256; ofs <<= 1) {
        int v = (t >= ofs) ? s[t - ofs] : 0;
        __syncthreads();
        s[t] += v;
        __syncthreads();
    }
    if (i < N) off[i] = s[t] - d;
    if (t == 255) partial[blockIdx.x] = s[255];
}

__global__ void scan23(int* __restrict__ off, const int* __restrict__ partial,
                       int* __restrict__ cursor, int N, int E, int nb) {
    __shared__ int s[256];
    __shared__ int ex[256];
    const int t = threadIdx.x;
    int d = (t < nb) ? partial[t] : 0;
    s[t] = d;
    __syncthreads();
#pragma unroll
    for (int ofs = 1; ofs < 256; ofs <<= 1) {
        int v = (t >= ofs) ? s[t - ofs] : 0;
        __syncthreads();
        s[t] += v;
        __syncthreads();
    }
    ex[t] = s[t] - d;
    __syncthreads();
    int i = blockIdx.x * 256 + t;
    if (i < N) {
        int v = off[i] + ex[i >> 8];
        off[i] = v;
        cursor[i] = v;
    } else if (i == N) {
        off[N] = E;
    }
}

// ---------------- fused: CSR fill + x -> fp8*dinv ----------------

__global__ void fill_cvt(const int* __restrict__ src, const int* __restrict__ dst,
                         int* __restrict__ cursor, int* __restrict__ srcs, int E,
                         const float* __restrict__ x, const float* __restrict__ dinv,
                         ushort_t* __restrict__ xb, int pairs) {
    int i = blockIdx.x * blockDim.x + threadIdx.x;
    if (i < E) { int p = atomicAdd(&cursor[dst[i]], 1); srcs[p] = src[i]; return; }
    i -= E;
    if (i < pairs) {
        float dr = dinv[i >> 6];                      // row = 2i/128
        float a = x[2 * i] * dr, b = x[2 * i + 1] * dr;
        uint_t d = __builtin_amdgcn_cvt_pk_fp8_f32(a, b, 0, false);
        xb[i] = (ushort_t)(d & 0xffffu);
    }
}

// ---------------- aggregation: fp8 gather, multi-edge wave-instructions ----------------
// R16 structure (proven in the 362us build): 4 gathers in flight (deeper ILP
// regressed, R15; col-chunking for locality regressed, R19 — it's not L3-BW
// bound). Output bf16 (GEMM A operand read exactly once, R16). R21: acc16
// pk-accumulate replaces scalar adds (-33% inner-loop VALU).

__global__ __launch_bounds__(256) void csr_agg_512(
        const uchar_t* __restrict__ xs, const int* __restrict__ off,
        const int* __restrict__ srcs, const float* __restrict__ dinv,
        ushort_t* __restrict__ ax, int N) {
    int gtid = blockIdx.x * 256 + threadIdx.x;
    int r = gtid >> 6, lane = gtid & 63;
    if (r >= N) return;
    const int half = lane >> 5, l32 = lane & 31;
    const uint4* xb = (const uint4*)xs;    // row stride = 32 uint4 (512 B)
    f32x2 a[8];
#pragma unroll
    for (int q = 0; q < 8; q++) a[q] = (f32x2){0.f, 0.f};
    if (half == 0) {
        uint4 v = xb[(size_t)r * 32 + l32];
        acc16(v, a);
    }
    int e = off[r];
    const int e1 = off[r + 1];
    for (; e + 8 <= e1; e += 8) {
        int si[4]; uint4 vi[4];
#pragma unroll
        for (int j = 0; j < 4; j++) si[j] = srcs[e + 2 * j + half];
#pragma unroll
        for (int j = 0; j < 4; j++) vi[j] = xb[(size_t)si[j] * 32 + l32];
#pragma unroll
        for (int j = 0; j < 4; j++) acc16(vi[j], a);
    }
    for (; e < e1; e += 2) {
        int idx = e + half;
        bool valid = idx < e1;
        int s = srcs[valid ? idx : e];
        uint4 v = xb[(size_t)s * 32 + l32];
        if (!valid) { v.x = 0; v.y = 0; v.z = 0; v.w = 0; }
        acc16(v, a);
    }
#pragma unroll
    for (int q = 0; q < 8; q++) {
        a[q][0] += __shfl_xor(a[q][0], 32);
        a[q][1] += __shfl_xor(a[q][1], 32);
    }
    {
        // both halves hold full sums; half0 stores cols l32*16+0..7,
        // half1 stores cols l32*16+8..15 -> contiguous 1KB per wave
        float dr = dinv[r];
        const int b = half * 4;            // f32x2 index base
        uint_t w0 = (uint_t)f2bf(a[b + 0][0] * dr) | ((uint_t)f2bf(a[b + 0][1] * dr) << 16);
        uint_t w1 = (uint_t)f2bf(a[b + 1][0] * dr) | ((uint_t)f2bf(a[b + 1][1] * dr) << 16);
        uint_t w2 = (uint_t)f2bf(a[b + 2][0] * dr) | ((uint_t)f2bf(a[b + 2][1] * dr) << 16);
        uint_t w3 = (uint_t)f2bf(a[b + 3][0] * dr) | ((uint_t)f2bf(a[b + 3][1] * dr) << 16);
        ((uint4*)ax)[(size_t)r * 64 + l32 * 2 + half] = make_uint4(w0, w1, w2, w3);
    }
}

__global__ __launch_bounds__(256) void csr_agg_128(
        const uchar_t* __restrict__ xs, const int* __restrict__ off,
        const int* __restrict__ srcs, const float* __restrict__ dinv,
        ushort_t* __restrict__ ax, int N) {
    int gtid = blockIdx.x * 256 + threadIdx.x;
    int r = gtid >> 6, lane = gtid & 63;
    if (r >= N) return;
    const int sub = lane >> 3, l8 = lane & 7;   // 8 edge slots x 8 col-chunks (16B)
    const uint4* xb = (const uint4*)xs;         // row stride = 8 uint4 (128 B)
    f32x2 a[8];
#pragma unroll
    for (int q = 0; q < 8; q++) a[q] = (f32x2){0.f, 0.f};
    if (sub == 0) {
        uint4 v = xb[(size_t)r * 8 + l8];
        acc16(v, a);
    }
    const int e1 = off[r + 1];
    for (int e = off[r]; e < e1; e += 8) {
        int idx = e + sub;
        bool valid = idx < e1;
        int s = srcs[valid ? idx : e];
        uint4 v = xb[(size_t)s * 8 + l8];
        if (!valid) { v.x = 0; v.y = 0; v.z = 0; v.w = 0; }
        acc16(v, a);
    }
#pragma unroll
    for (int q = 0; q < 8; q++) {
        a[q][0] += __shfl_xor(a[q][0], 8);  a[q][1] += __shfl_xor(a[q][1], 8);
        a[q][0] += __shfl_xor(a[q][0], 16); a[q][1] += __shfl_xor(a[q][1], 16);
        a[q][0] += __shfl_xor(a[q][0], 32); a[q][1] += __shfl_xor(a[q][1], 32);
    }
    if (sub < 2) {
        float dr = dinv[r];
        const int b = sub * 4;
        uint_t w0 = (uint_t)f2bf(a[b + 0][0] * dr) | ((uint_t)f2bf(a[b + 0][1] * dr) << 16);
        uint_t w1 = (uint_t)f2bf(a[b + 1][0] * dr) | ((uint_t)f2bf(a[b + 1][1] * dr) << 16);
        uint_t w2 = (uint_t)f2bf(a[b + 2][0] * dr) | ((uint_t)f2bf(a[b + 2][1] * dr) << 16);
        uint_t w3 = (uint_t)f2bf(a[b + 3][0] * dr) | ((uint_t)f2bf(a[b + 3][1] * dr) << 16);
        ((uint4*)ax)[(size_t)r * 16 + l8 * 2 + sub] = make_uint4(w0, w1, w2, w3);
    }
}

// ---------------- MFMA GEMM: C = A(bf16)[M x K] @ Wt(bf16)[512 x K]^T + bias, bf16 out ----
// R16-proven structure: 128x128 tile, BK=64, 4 waves (64x64 each, 4x4 frags of
// 16x16x32 bf16). Both operands staged via global_load_lds with CONTIGUOUS
// 8-row calls + XOR chunk-swizzle (linear LDS dest, pre-swizzled global source
// chunk c^(row&7), same XOR on ds_read addr). XCD swizzle: the 4 n-blocks
// sharing an m-tile map to the same XCD (id%8) so A-tile re-reads hit that
// XCD's L2. Fused-LN variants (R17-R20) all lost to this — keep split.

__global__ __launch_bounds__(256) void gemm_mfma(
        const ushort_t* __restrict__ A, const ushort_t* __restrict__ Wt,
        const float* __restrict__ bias, ushort_t* __restrict__ C, int M, int K, int MB) {
    __shared__ __align__(16) ushort_t AsL[128 * 64];   // 16 KB row-major, swizzled chunks
    __shared__ __align__(16) ushort_t BsL[128 * 64];   // 16 KB
    const int id = blockIdx.x;
    const int mb = (id >> 5) * 8 + (id & 7);
    const int nbk = (id >> 3) & 3;
    if (mb >= MB) return;
    const int t = threadIdx.x;
    const int wave = t >> 6, lane = t & 63;
    const int m0 = mb * 128, n0 = nbk * 128;
    const int wm = (wave & 1) * 64, wn = (wave >> 1) * 64;
    const int quad = lane >> 4, l16 = lane & 15;
    const int srow = lane >> 3;                // 0..7 within the 8-row stage group
    const int schunk = (lane & 7) ^ srow;      // pre-swizzled source 16B chunk
    const int sw = (l16 & 7) << 4;             // read-side XOR (bytes)

    f32x4 acc[4][4];
#pragma unroll
    for (int i = 0; i < 4; i++)
#pragma unroll
        for (int j = 0; j < 4; j++) acc[i][j] = (f32x4){0.f, 0.f, 0.f, 0.f};

    for (int k0 = 0; k0 < K; k0 += 64) {
#pragma unroll
        for (int j = 0; j < 4; j++) {
            const int c = wave * 4 + j;        // 8-row group 0..15
            int gm = m0 + 8 * c + srow;
            if (gm >= M) gm = M - 1;
            gload_lds16(A + (size_t)gm * K + k0 + (schunk << 3), AsL + c * 512);
            gload_lds16(Wt + (size_t)(n0 + 8 * c + srow) * K + k0 + (schunk << 3),
                        BsL + c * 512);
        }
        __syncthreads();
#pragma unroll
        for (int kk = 0; kk < 2; kk++) {
            const int kb = (kk * 4 + quad) << 4;
            bf16x8 af[4], bfr[4];
#pragma unroll
            for (int jn = 0; jn < 4; jn++)
                bfr[jn] = *(const bf16x8*)((const char*)BsL
                              + (wn + jn * 16 + l16) * 128 + (kb ^ sw));
#pragma unroll
            for (int i = 0; i < 4; i++)
                af[i] = *(const bf16x8*)((const char*)AsL
                              + (wm + i * 16 + l16) * 128 + (kb ^ sw));
#pragma unroll
            for (int i = 0; i < 4; i++)
#pragma unroll
                for (int jn = 0; jn < 4; jn++)
                    acc[i][jn] = __builtin_amdgcn_mfma_f32_16x16x32_bf16(
                                     af[i], bfr[jn], acc[i][jn], 0, 0, 0);
        }
        __syncthreads();
    }
    // epilogue: + bias, pack bf16. D: col = lane&15, row = quad*4 + reg
#pragma unroll
    for (int i = 0; i < 4; i++) {
#pragma unroll
        for (int jn = 0; jn < 4; jn++) {
            int gn = n0 + wn + jn * 16 + l16;
            float bv = bias[gn];
#pragma unroll
            for (int rg = 0; rg < 4; rg++) {
                int gm = m0 + wm + i * 16 + quad * 4 + rg;
                if (gm < M) C[(size_t)gm * HID + gn] = f2bf(acc[i][jn][rg] + bv);
            }
        }
    }
}

// ---------------- LayerNorm + ReLU -> fp8 out, pre-scaled by dinv (layers 0-2) ----------------

__global__ void ln_relu(const ushort_t* __restrict__ h, const float* __restrict__ gamma,
                        const float* __restrict__ beta, const float* __restrict__ dinv,
                        void* __restrict__ optr, int N) {
    int gtid = blockIdx.x * blockDim.x + threadIdx.x;
    int r = gtid >> 6, lane = gtid & 63;
    if (r >= N) return;
    uint4 v = ((const uint4*)(h + (size_t)r * HID))[lane];
    float f[8] = {bflo(v.x), bfhi(v.x), bflo(v.y), bfhi(v.y),
                  bflo(v.z), bfhi(v.z), bflo(v.w), bfhi(v.w)};
    float s = 0.f, q = 0.f;
#pragma unroll
    for (int j = 0; j < 8; j++) { s += f[j]; q += f[j] * f[j]; }
#pragma unroll
    for (int ofs = 32; ofs > 0; ofs >>= 1) {
        s += __shfl_xor(s, ofs);
        q += __shfl_xor(q, ofs);
    }
    float mu  = s * (1.0f / HID);
    float var = q * (1.0f / HID) - mu * mu;
    float rs  = rsqrtf(var + EPSV);
    float dr  = dinv[r];
    const float4* gp = (const float4*)gamma;
    const float4* bp = (const float4*)beta;
    float4 g0 = gp[2 * lane], g1 = gp[2 * lane + 1];
    float4 b0 = bp[2 * lane], b1 = bp[2 * lane + 1];
    float gg[8] = {g0.x, g0.y, g0.z, g0.w, g1.x, g1.y, g1.z, g1.w};
    float bb[8] = {b0.x, b0.y, b0.z, b0.w, b1.x, b1.y, b1.z, b1.w};
    float o[8];
#pragma unroll
    for (int j = 0; j < 8; j++)
        o[j] = fmaxf((f[j] - mu) * rs * gg[j] + bb[j], 0.f) * dr;
    uint2 ov;
    ov.x = enc4(o[0], o[1], o[2], o[3]);
    ov.y = enc4(o[4], o[5], o[6], o[7]);
    ((uint2*)optr)[(size_t)r * 64 + lane] = ov;   // fp8 row: 8 B/lane
}

// ---------------- fused layer-3 LN+ReLU + mean pool — NO atomics ----------------

__global__ __launch_bounds__(256) void ln_pool(
        const ushort_t* __restrict__ h, const float* __restrict__ gamma,
        const float* __restrict__ beta, float* __restrict__ pbuf, int N) {
    __shared__ float sred[4][64][8];
    const int t = threadIdx.x;
    const int sub = t >> 6, lane = t & 63;
    const float4* gp = (const float4*)gamma;
    const float4* bp = (const float4*)beta;
    float4 g0 = gp[2 * lane], g1 = gp[2 * lane + 1];
    float4 b0 = bp[2 * lane], b1 = bp[2 * lane + 1];
    float gg[8] = {g0.x, g0.y, g0.z, g0.w, g1.x, g1.y, g1.z, g1.w};
    float bb[8] = {b0.x, b0.y, b0.z, b0.w, b1.x, b1.y, b1.z, b1.w};
    float colacc[8] = {0.f, 0.f, 0.f, 0.f, 0.f, 0.f, 0.f, 0.f};
    const int step = PB * 4;
    for (int r = blockIdx.x * 4 + sub; r < N; r += step) {
        uint4 v = ((const uint4*)(h + (size_t)r * HID))[lane];
        float f[8] = {bflo(v.x), bfhi(v.x), bflo(v.y), bfhi(v.y),
                      bflo(v.z), bfhi(v.z), bflo(v.w), bfhi(v.w)};
        float s = 0.f, q = 0.f;
#pragma unroll
        for (int j = 0; j < 8; j++) { s += f[j]; q += f[j] * f[j]; }
#pragma unroll
        for (int ofs = 32; ofs > 0; ofs >>= 1) {
            s += __shfl_xor(s, ofs);
            q += __shfl_xor(q, ofs);
        }
        float mu  = s * (1.0f / HID);
        float var = q * (1.0f / HID) - mu * mu;
        float rs  = rsqrtf(var + EPSV);
#pragma unroll
        for (int j = 0; j < 8; j++)
            colacc[j] += fmaxf((f[j] - mu) * rs * gg[j] + bb[j], 0.f);
    }
#pragma unroll
    for (int j = 0; j < 8; j++) sred[sub][lane][j] = colacc[j];
    __syncthreads();
    if (sub == 0) {
        float4 o0, o1;
        o0.x = sred[0][lane][0] + sred[1][lane][0] + sred[2][lane][0] + sred[3][lane][0];
        o0.y = sred[0][lane][1] + sred[1][lane][1] + sred[2][lane][1] + sred[3][lane][1];
        o0.z = sred[0][lane][2] + sred[1][lane][2] + sred[2][lane][2] + sred[3][lane][2];
        o0.w = sred[0][lane][3] + sred[1][lane][3] + sred[2][lane][3] + sred[3][lane][3];
        o1.x = sred[0][lane][4] + sred[1][lane][4] + sred[2][lane][4] + sred[3][lane][4];
        o1.y = sred[0][lane][5] + sred[1][lane][5] + sred[2][lane][5] + sred[3][lane][5];
        o1.z = sred[0][lane][6] + sred[1][lane][6] + sred[2][lane][6] + sred[3][lane][6];
        o1.w = sred[0][lane][7] + sred[1][lane][7] + sred[2][lane][7] + sred[3][lane][7];
        float* pb = pbuf + (size_t)blockIdx.x * HID + lane * 8;
        ((float4*)pb)[0] = o0;
        ((float4*)pb)[1] = o1;
    }
}

// ---------------- hierarchical pool partial reduction: PB rows -> PR rows ----------------

__global__ __launch_bounds__(256) void pool_reduce(
        const float* __restrict__ pbuf, float* __restrict__ pbuf2) {
    const int t = threadIdx.x;
    const int b = blockIdx.x;
    const int R = PB / PR;   // 8 rows per block
    float2 s = make_float2(0.f, 0.f);
#pragma unroll
    for (int u = 0; u < R; u++) {
        const float2 v = ((const float2*)(pbuf + (size_t)(b * R + u) * HID))[t];
        s.x += v.x; s.y += v.y;
    }
    ((float2*)(pbuf2 + (size_t)b * HID))[t] = s;
}

// ---------------- output head: reduce PR partials + project to 7 outs ----------------

__global__ void out_kernel(const float* __restrict__ pbuf2, const float* __restrict__ Wout,
                           const float* __restrict__ bout, float* __restrict__ out, int N) {
    __shared__ float red[256];
    int t = threadIdx.x;
    float g0 = 0.f, g1 = 0.f;
#pragma unroll
    for (int p = 0; p < PR; p += 8) {
#pragma unroll
        for (int u = 0; u < 8; u++) {
            const float2 v = ((const float2*)(pbuf2 + (size_t)(p + u) * HID))[t];
            g0 += v.x; g1 += v.y;
        }
    }
    float invn = 1.0f / (float)N;
    for (int o = 0; o < OUTD; o++) {
        float pr = g0 * Wout[(2 * t) * OUTD + o] + g1 * Wout[(2 * t + 1) * OUTD + o];
        red[t] = pr;
        __syncthreads();
        for (int sft = 128; sft > 0; sft >>= 1) {
            if (t < sft) red[t] += red[t + sft];
            __syncthreads();
        }
        if (t == 0) out[o] = red[0] * invn + bout[o];
        __syncthreads();
    }
}

// ---------------- launch ----------------

extern "C" void kernel_launch(void* const* d_in, const int* in_sizes, int n_in,
                              void* d_out, int out_size, void* d_ws, size_t ws_size,
                              hipStream_t stream) {
    const float* x  = (const float*)d_in[0];
    const int*   ei = (const int*)d_in[1];
    const int N = in_sizes[0] / 128;
    const int E = in_sizes[1] / 2;
    const int* src = ei;
    const int* dst = ei + E;
    const float* Ws[4] = {(const float*)d_in[2], (const float*)d_in[4],
                          (const float*)d_in[6], (const float*)d_in[8]};
    const float* bs[4] = {(const float*)d_in[3], (const float*)d_in[5],
                          (const float*)d_in[7], (const float*)d_in[9]};
    const float* gamma = (const float*)d_in[10];
    const float* beta  = (const float*)d_in[11];
    const float* Wout  = (const float*)d_in[12];
    const float* bout  = (const float*)d_in[13];
    float* out = (float*)d_out;

    // workspace layout (16B-aligned chunks first)
    char* p = (char*)d_ws;
    ushort_t* axb = (ushort_t*)p;  p += sizeof(ushort_t) * (size_t)N * HID;   // agg out bf16 (gemm A)
    ushort_t* hb  = (ushort_t*)p;  p += sizeof(ushort_t) * (size_t)N * HID;   // gemm out bf16
    uchar_t*  ho8 = (uchar_t*)p;   p += (size_t)N * HID;                      // fp8 LN out (agg input)
    uchar_t*  xb8 = ho8;           // alias: fp8 x (N*128B, pre-scaled) until ln(l0) overwrites
    ushort_t* Wt[4];
    Wt[0] = (ushort_t*)p;          p += sizeof(ushort_t) * 128 * HID;
    Wt[1] = (ushort_t*)p;          p += sizeof(ushort_t) * HID * HID;
    Wt[2] = (ushort_t*)p;          p += sizeof(ushort_t) * HID * HID;
    Wt[3] = (ushort_t*)p;          p += sizeof(ushort_t) * HID * HID;
    float* dinv  = (float*)p;      p += sizeof(float) * N;
    float* pbuf  = (float*)p;      p += sizeof(float) * PB * HID;             // 512 KB pool partials
    float* pbuf2 = (float*)p;      p += sizeof(float) * PR * HID;             // 64 KB stage-2
    int* deg    = (int*)p;         p += sizeof(int) * N;
    int* off    = (int*)p;         p += sizeof(int) * (N + 4);
    int* cursor = (int*)p;         p += sizeof(int) * N;
    int* partial= (int*)p;         p += sizeof(int) * 256;
    int* srcs   = (int*)p;         // E ints

    const int nb = (N + 255) / 256;
    const int MB = (N + 127) / 128;                  // gemm m-tiles
    const int gemm_blocks = 32 * ((MB + 7) / 8);     // XCD-swizzled flat grid
    const int degB = (E + 255) / 256;

    // ---- setup: CSR build + conversions (once) ----
    hipMemsetAsync(deg, 0, sizeof(int) * N, stream);   // memset node: graph-capturable
    deg_wtrans<<<degB + 832, 256, 0, stream>>>(dst, deg, E, degB,
                                               Ws[0], Ws[1], Ws[2], Ws[3],
                                               Wt[0], Wt[1], Wt[2], Wt[3]);
    scan1<<<nb, 256, 0, stream>>>(deg, off, partial, dinv, N);
    scan23<<<(N + 256) / 256, 256, 0, stream>>>(off, partial, cursor, N, E, nb);
    {
        int pairs = N * 64;   // N*128/2
        int tot = E + pairs;
        fill_cvt<<<(tot + 255) / 256, 256, 0, stream>>>(src, dst, cursor, srcs, E,
                                                        x, dinv, (ushort_t*)xb8, pairs);
    }

    for (int l = 0; l < 4; l++) {
        const int K = (l == 0) ? 128 : HID;
        if (l == 0)
            csr_agg_128<<<(N * 64 + 255) / 256, 256, 0, stream>>>(xb8, off, srcs, dinv, axb, N);
        else
            csr_agg_512<<<(N * 64 + 255) / 256, 256, 0, stream>>>(ho8, off, srcs, dinv, axb, N);
        gemm_mfma<<<gemm_blocks, 256, 0, stream>>>(axb, Wt[l], bs[l], hb, N, K, MB);
        if (l < 3)
            ln_relu<<<(N * 64 + 255) / 256, 256, 0, stream>>>(hb, gamma, beta, dinv, ho8, N);
        else
            ln_pool<<<PB, 256, 0, stream>>>(hb, gamma, beta, pbuf, N);
    }
    pool_reduce<<<PR, 256, 0, stream>>>(pbuf, pbuf2);
    out_kernel<<<1, 256, 0, stream>>>(pbuf2, Wout, bout, out, N);
}